// Round 2
// baseline (346.325 us; speedup 1.0000x reference)
//
#include <hip/hip_runtime.h>

typedef __bf16 bf16x8 __attribute__((ext_vector_type(8)));
typedef __bf16 bf16x4v __attribute__((ext_vector_type(4)));
typedef float floatx4 __attribute__((ext_vector_type(4)));

#define B_ 4
#define S_ 1024
#define E_ 768
#define H_ 12
#define HD_ 64

__device__ __forceinline__ void async16(const void* g, void* l) {
  __builtin_amdgcn_global_load_lds((const __attribute__((address_space(1))) void*)g,
                                   (__attribute__((address_space(3))) void*)l, 16, 0, 0);
}

__device__ __forceinline__ floatx4 mfma16(bf16x8 a, bf16x8 b, floatx4 c) {
  return __builtin_amdgcn_mfma_f32_16x16x32_bf16(a, b, c, 0, 0, 0);
}

// ---------------- fp32 -> bf16 conversion ----------------
__global__ __launch_bounds__(256) void cvt_in_kernel(
    const float* __restrict__ q, const float* __restrict__ k,
    const float* __restrict__ v, __bf16* __restrict__ dst) {
  const int z = blockIdx.z;
  const float* s = (z == 0) ? q : (z == 1) ? k : v;
  __bf16* d = dst + (size_t)z * (size_t)(B_ * S_ * E_);
  const size_t i8 = (size_t)blockIdx.x * 256 + threadIdx.x;
  const float4* sp = (const float4*)s + i8 * 2;
  float4 a = sp[0], b = sp[1];
  bf16x8 o;
  o[0] = (__bf16)a.x; o[1] = (__bf16)a.y; o[2] = (__bf16)a.z; o[3] = (__bf16)a.w;
  o[4] = (__bf16)b.x; o[5] = (__bf16)b.y; o[6] = (__bf16)b.z; o[7] = (__bf16)b.w;
  *(bf16x8*)(d + i8 * 8) = o;
}

__global__ __launch_bounds__(256) void cvt_w_kernel(
    const float* __restrict__ w0, const float* __restrict__ w1,
    const float* __restrict__ w2, const float* __restrict__ w3,
    __bf16* __restrict__ dst) {
  const int z = blockIdx.z;
  const float* s = (z == 0) ? w0 : (z == 1) ? w1 : (z == 2) ? w2 : w3;
  __bf16* d = dst + (size_t)z * (size_t)(E_ * E_);
  const size_t i8 = (size_t)blockIdx.x * 256 + threadIdx.x;
  const float4* sp = (const float4*)s + i8 * 2;
  float4 a = sp[0], b = sp[1];
  bf16x8 o;
  o[0] = (__bf16)a.x; o[1] = (__bf16)a.y; o[2] = (__bf16)a.z; o[3] = (__bf16)a.w;
  o[4] = (__bf16)b.x; o[5] = (__bf16)b.y; o[6] = (__bf16)b.z; o[7] = (__bf16)b.w;
  *(bf16x8*)(d + i8 * 8) = o;
}

// ---------------- QKV projection GEMM ----------------
// y = X @ W^T + bias ; X [4096,768] bf16, W [768,768] bf16 (row n = output feat)
// z=0 -> Qh [B,H,S,HD] scaled by 0.125 ; z=1 -> Kh [B,H,S,HD] ; z=2 -> Vt [B,H,HD,S]
__global__ __launch_bounds__(256, 3) void proj_qkv_kernel(
    const __bf16* __restrict__ Xq, const __bf16* __restrict__ Xk, const __bf16* __restrict__ Xv,
    const __bf16* __restrict__ Wq, const __bf16* __restrict__ Wk, const __bf16* __restrict__ Wv,
    const float* __restrict__ bq, const float* __restrict__ bk, const float* __restrict__ bv,
    __bf16* __restrict__ Qh, __bf16* __restrict__ Kh, __bf16* __restrict__ Vt) {
  const int z = blockIdx.z;
  const __bf16* X = (z == 0) ? Xq : (z == 1) ? Xk : Xv;
  const __bf16* W = (z == 0) ? Wq : (z == 1) ? Wk : Wv;
  const float* bias = (z == 0) ? bq : (z == 1) ? bk : bv;

  const int tid = threadIdx.x;
  const int wave = tid >> 6, lane = tid & 63;
  const int l15 = lane & 15, quad = lane >> 4;
  const int wr = wave >> 1, wc = wave & 1;
  const int bm = blockIdx.y * 128, bn = blockIdx.x * 128;

  __shared__ alignas(16) __bf16 As[128 * 32];
  __shared__ alignas(16) __bf16 Bs[128 * 32];

  floatx4 zf = {0.0f, 0.0f, 0.0f, 0.0f};
  floatx4 acc[4][4];
#pragma unroll
  for (int i = 0; i < 4; ++i)
#pragma unroll
    for (int j = 0; j < 4; ++j) acc[i][j] = zf;

  for (int kk = 0; kk < E_; kk += 32) {
#pragma unroll
    for (int c = 0; c < 2; ++c) {
      const int f = c * 256 + tid;
      const int r = f >> 2, kq = f & 3;
      async16(X + (size_t)(bm + r) * E_ + kk + kq * 8, &As[(c * 4 + wave) * 512]);
      async16(W + (size_t)(bn + r) * E_ + kk + kq * 8, &Bs[(c * 4 + wave) * 512]);
    }
    __syncthreads();
    bf16x8 af[4], bfr[4];
#pragma unroll
    for (int i = 0; i < 4; ++i)
      af[i] = *(const bf16x8*)&As[(wr * 64 + i * 16 + l15) * 32 + quad * 8];
#pragma unroll
    for (int j = 0; j < 4; ++j)
      bfr[j] = *(const bf16x8*)&Bs[(wc * 64 + j * 16 + l15) * 32 + quad * 8];
#pragma unroll
    for (int i = 0; i < 4; ++i)
#pragma unroll
      for (int j = 0; j < 4; ++j)
        acc[i][j] = mfma16(af[i], bfr[j], acc[i][j]);
    __syncthreads();
  }

#pragma unroll
  for (int j = 0; j < 4; ++j) {
    const int n = bn + wc * 64 + j * 16 + l15;
    const float bval = bias[n];
    const int hh = n >> 6, dd = n & 63;
    if (z < 2) {
      __bf16* dst = (z == 0) ? Qh : Kh;
      const float sc = (z == 0) ? 0.125f : 1.0f;
#pragma unroll
      for (int i = 0; i < 4; ++i) {
#pragma unroll
        for (int r = 0; r < 4; ++r) {
          const int m = bm + wr * 64 + i * 16 + quad * 4 + r;
          const int bb = m >> 10, ss = m & 1023;
          const float val = (acc[i][j][r] + bval) * sc;
          dst[(((size_t)bb * H_ + hh) * S_ + ss) * HD_ + dd] = (__bf16)val;
        }
      }
    } else {
#pragma unroll
      for (int i = 0; i < 4; ++i) {
        const int m0 = bm + wr * 64 + i * 16 + quad * 4;
        const int bb = m0 >> 10, ss0 = m0 & 1023;
        bf16x4v pk;
#pragma unroll
        for (int r = 0; r < 4; ++r) pk[r] = (__bf16)(acc[i][j][r] + bval);
        *(bf16x4v*)&Vt[(((size_t)bb * H_ + hh) * HD_ + dd) * S_ + ss0] = pk;
      }
    }
  }
}

// ---------------- output projection GEMM ----------------
__global__ __launch_bounds__(256, 3) void proj_out_kernel(
    const __bf16* __restrict__ X, const __bf16* __restrict__ W,
    const float* __restrict__ bias, float* __restrict__ out) {
  const int tid = threadIdx.x;
  const int wave = tid >> 6, lane = tid & 63;
  const int l15 = lane & 15, quad = lane >> 4;
  const int wr = wave >> 1, wc = wave & 1;
  const int bm = blockIdx.y * 128, bn = blockIdx.x * 128;

  __shared__ alignas(16) __bf16 As[128 * 32];
  __shared__ alignas(16) __bf16 Bs[128 * 32];

  floatx4 zf = {0.0f, 0.0f, 0.0f, 0.0f};
  floatx4 acc[4][4];
#pragma unroll
  for (int i = 0; i < 4; ++i)
#pragma unroll
    for (int j = 0; j < 4; ++j) acc[i][j] = zf;

  for (int kk = 0; kk < E_; kk += 32) {
#pragma unroll
    for (int c = 0; c < 2; ++c) {
      const int f = c * 256 + tid;
      const int r = f >> 2, kq = f & 3;
      async16(X + (size_t)(bm + r) * E_ + kk + kq * 8, &As[(c * 4 + wave) * 512]);
      async16(W + (size_t)(bn + r) * E_ + kk + kq * 8, &Bs[(c * 4 + wave) * 512]);
    }
    __syncthreads();
    bf16x8 af[4], bfr[4];
#pragma unroll
    for (int i = 0; i < 4; ++i)
      af[i] = *(const bf16x8*)&As[(wr * 64 + i * 16 + l15) * 32 + quad * 8];
#pragma unroll
    for (int j = 0; j < 4; ++j)
      bfr[j] = *(const bf16x8*)&Bs[(wc * 64 + j * 16 + l15) * 32 + quad * 8];
#pragma unroll
    for (int i = 0; i < 4; ++i)
#pragma unroll
      for (int j = 0; j < 4; ++j)
        acc[i][j] = mfma16(af[i], bfr[j], acc[i][j]);
    __syncthreads();
  }

#pragma unroll
  for (int j = 0; j < 4; ++j) {
    const int n = bn + wc * 64 + j * 16 + l15;
    const float bval = bias[n];
#pragma unroll
    for (int i = 0; i < 4; ++i) {
#pragma unroll
      for (int r = 0; r < 4; ++r) {
        const int m = bm + wr * 64 + i * 16 + quad * 4 + r;
        out[(size_t)m * E_ + n] = acc[i][j][r] + bval;
      }
    }
  }
}

// ---------------- fused flash attention ----------------
// grid (8, 48): x = q-tile (128 rows), y = b*12+h. 4 waves, 32 q-rows each.
// Qh/Kh [B,H,S,64] (Q pre-scaled by 0.125), Vt [B,H,64,S], mask [B,S,S] int.
// K-tile = 64 keys/iter. LDS: Qs 16K + Ks 8K + Vs 8K + Ps 16K = 48 KB.
#define NEG_BIG (-1e30f)
__global__ __launch_bounds__(256, 2) void attn_kernel(
    const __bf16* __restrict__ Qh, const __bf16* __restrict__ Kh,
    const __bf16* __restrict__ Vt, const int* __restrict__ mask,
    __bf16* __restrict__ XV) {
  const int tid = threadIdx.x;
  const int wave = tid >> 6, lane = tid & 63;
  const int l15 = lane & 15, quad = lane >> 4;
  const int bh = blockIdx.y;
  const int b = bh / H_, h = bh % H_;
  const int q0 = blockIdx.x * 128;
  const int wq0 = wave * 32;

  __shared__ alignas(16) __bf16 Qs[128 * 64];  // q x d        (16 KB)
  __shared__ alignas(16) __bf16 Ks[64 * 64];   // key x d      ( 8 KB)
  __shared__ alignas(16) __bf16 Vs[64 * 64];   // d x key      ( 8 KB)
  __shared__ alignas(16) __bf16 Ps[4 * 32 * 64];  // per-wave P (16 KB)

  // stage Q tile once (128 rows x 64 d)
  const __bf16* qbase = Qh + ((size_t)bh * S_ + q0) * HD_;
#pragma unroll
  for (int c = 0; c < 4; ++c) {
    const int f = c * 256 + tid;
    const int row = f >> 3, kq = f & 7;
    async16(qbase + (size_t)row * HD_ + kq * 8, &Qs[(c * 4 + wave) * 512]);
  }

  floatx4 zf = {0.0f, 0.0f, 0.0f, 0.0f};
  floatx4 o[2][4];
  float mrow[2][4], lrow[2][4];
#pragma unroll
  for (int i = 0; i < 2; ++i) {
#pragma unroll
    for (int jd = 0; jd < 4; ++jd) o[i][jd] = zf;
#pragma unroll
    for (int r = 0; r < 4; ++r) { mrow[i][r] = NEG_BIG; lrow[i][r] = 0.0f; }
  }

  const int* mbase = mask + ((size_t)b * S_ + q0 + wq0) * S_;
  __bf16* Pw = &Ps[wave * 2048];

  for (int kt = 0; kt < 16; ++kt) {
    const int k0 = kt * 64;
    __syncthreads();  // prior iter's Ks/Vs reads complete before restaging
    const __bf16* kbase = Kh + ((size_t)bh * S_ + k0) * HD_;
#pragma unroll
    for (int c = 0; c < 2; ++c) {
      const int f = c * 256 + tid;
      const int row = f >> 3, kq = f & 7;
      async16(kbase + (size_t)row * HD_ + kq * 8, &Ks[(c * 4 + wave) * 512]);
    }
    const __bf16* vbase = Vt + (size_t)bh * HD_ * S_ + k0;
#pragma unroll
    for (int c = 0; c < 2; ++c) {
      const int f = c * 256 + tid;
      const int row = f >> 3, cq = f & 7;
      async16(vbase + (size_t)row * S_ + cq * 8, &Vs[(c * 4 + wave) * 512]);
    }
    __syncthreads();  // staging visible (covers Q on first iter)

    // ---- scores: S = Q K^T (Q pre-scaled by 1/8) ----
    bf16x8 af[2][2];
#pragma unroll
    for (int i = 0; i < 2; ++i)
#pragma unroll
      for (int ks = 0; ks < 2; ++ks)
        af[i][ks] = *(const bf16x8*)&Qs[(wq0 + i * 16 + l15) * 64 + ks * 32 + quad * 8];
    floatx4 sc[2][4];
#pragma unroll
    for (int i = 0; i < 2; ++i)
#pragma unroll
      for (int j = 0; j < 4; ++j) sc[i][j] = zf;
#pragma unroll
    for (int j = 0; j < 4; ++j) {
      bf16x8 b0 = *(const bf16x8*)&Ks[(j * 16 + l15) * 64 + 0 * 32 + quad * 8];
      bf16x8 b1 = *(const bf16x8*)&Ks[(j * 16 + l15) * 64 + 1 * 32 + quad * 8];
#pragma unroll
      for (int i = 0; i < 2; ++i) {
        sc[i][j] = mfma16(af[i][0], b0, sc[i][j]);
        sc[i][j] = mfma16(af[i][1], b1, sc[i][j]);
      }
    }

    // ---- mask + online softmax (stats per q-row, wave-local) ----
#pragma unroll
    for (int i = 0; i < 2; ++i) {
#pragma unroll
      for (int j = 0; j < 4; ++j)
#pragma unroll
        for (int r = 0; r < 4; ++r) {
          const int qq = i * 16 + quad * 4 + r;
          const int kk2 = k0 + j * 16 + l15;
          const int mv = mbase[(size_t)qq * S_ + kk2];
          sc[i][j][r] = mv ? sc[i][j][r] : NEG_BIG;
        }
      float tmax[4], tsum[4];
#pragma unroll
      for (int r = 0; r < 4; ++r) {
        float mx = sc[i][0][r];
#pragma unroll
        for (int j = 1; j < 4; ++j) mx = fmaxf(mx, sc[i][j][r]);
        tmax[r] = mx;
      }
#pragma unroll
      for (int sh = 1; sh < 16; sh <<= 1)
#pragma unroll
        for (int r = 0; r < 4; ++r) tmax[r] = fmaxf(tmax[r], __shfl_xor(tmax[r], sh, 64));
      float mnew[4], alpha[4];
#pragma unroll
      for (int r = 0; r < 4; ++r) {
        mnew[r] = fmaxf(mrow[i][r], tmax[r]);
        alpha[r] = __expf(mrow[i][r] - mnew[r]);
        mrow[i][r] = mnew[r];
        tsum[r] = 0.0f;
      }
#pragma unroll
      for (int j = 0; j < 4; ++j)
#pragma unroll
        for (int r = 0; r < 4; ++r) {
          const float p = __expf(sc[i][j][r] - mnew[r]);
          tsum[r] += p;
          Pw[(i * 16 + quad * 4 + r) * 64 + j * 16 + l15] = (__bf16)p;
        }
#pragma unroll
      for (int sh = 1; sh < 16; sh <<= 1)
#pragma unroll
        for (int r = 0; r < 4; ++r) tsum[r] += __shfl_xor(tsum[r], sh, 64);
#pragma unroll
      for (int r = 0; r < 4; ++r) lrow[i][r] = lrow[i][r] * alpha[r] + tsum[r];
#pragma unroll
      for (int jd = 0; jd < 4; ++jd)
#pragma unroll
        for (int r = 0; r < 4; ++r) o[i][jd][r] *= alpha[r];
    }

    // ---- O += P V (P wave-private; same-wave LDS write->read, in order) ----
#pragma unroll
    for (int ks2 = 0; ks2 < 2; ++ks2) {
      bf16x8 pa[2];
#pragma unroll
      for (int i = 0; i < 2; ++i)
        pa[i] = *(const bf16x8*)&Pw[(i * 16 + l15) * 64 + ks2 * 32 + quad * 8];
#pragma unroll
      for (int jd = 0; jd < 4; ++jd) {
        bf16x8 vb = *(const bf16x8*)&Vs[(jd * 16 + l15) * 64 + ks2 * 32 + quad * 8];
#pragma unroll
        for (int i = 0; i < 2; ++i) o[i][jd] = mfma16(pa[i], vb, o[i][jd]);
      }
    }
  }

  // ---- epilogue: normalize and store XV [B,S,E] bf16 ----
  float linv[2][4];
#pragma unroll
  for (int i = 0; i < 2; ++i)
#pragma unroll
    for (int r = 0; r < 4; ++r) linv[i][r] = (lrow[i][r] > 0.0f) ? (1.0f / lrow[i][r]) : 0.0f;
  __bf16* xbase = XV + ((size_t)b * S_ + q0 + wq0) * E_ + h * HD_;
#pragma unroll
  for (int i = 0; i < 2; ++i)
#pragma unroll
    for (int jd = 0; jd < 4; ++jd)
#pragma unroll
      for (int r = 0; r < 4; ++r) {
        const float v = o[i][jd][r] * linv[i][r];
        xbase[(size_t)(i * 16 + quad * 4 + r) * E_ + jd * 16 + l15] = (__bf16)v;
      }
}

extern "C" void kernel_launch(void* const* d_in, const int* in_sizes, int n_in,
                              void* d_out, int out_size, void* d_ws, size_t ws_size,
                              hipStream_t stream) {
  const float* query = (const float*)d_in[0];
  const float* key   = (const float*)d_in[1];
  const float* value = (const float*)d_in[2];
  const int*   mask  = (const int*)d_in[3];
  const float* Wq = (const float*)d_in[4];
  const float* bq = (const float*)d_in[5];
  const float* Wk = (const float*)d_in[6];
  const float* bk = (const float*)d_in[7];
  const float* Wv = (const float*)d_in[8];
  const float* bv = (const float*)d_in[9];
  const float* Wo = (const float*)d_in[10];
  const float* bo = (const float*)d_in[11];
  float* out = (float*)d_out;

  const size_t NX = (size_t)B_ * S_ * E_;  // 3145728
  const size_t NW = (size_t)E_ * E_;       // 589824
  __bf16* ws = (__bf16*)d_ws;
  __bf16* xq  = ws;
  __bf16* xk  = xq + NX;
  __bf16* xv  = xk + NX;
  __bf16* wqb = xv + NX;
  __bf16* wkb = wqb + NW;
  __bf16* wvb = wkb + NW;
  __bf16* wob = wvb + NW;
  __bf16* Qh  = wob + NW;
  __bf16* Kh  = Qh + NX;
  __bf16* Vt  = Kh + NX;
  __bf16* XVb = Vt + NX;

  cvt_in_kernel<<<dim3(1536, 1, 3), 256, 0, stream>>>(query, key, value, xq);
  cvt_w_kernel<<<dim3(288, 1, 4), 256, 0, stream>>>(Wq, Wk, Wv, Wo, wqb);
  proj_qkv_kernel<<<dim3(6, 32, 3), 256, 0, stream>>>(xq, xk, xv, wqb, wkb, wvb,
                                                      bq, bk, bv, Qh, Kh, Vt);
  attn_kernel<<<dim3(8, 48), 256, 0, stream>>>(Qh, Kh, Vt, mask, XVb);
  proj_out_kernel<<<dim3(6, 32), 256, 0, stream>>>(XVb, wob, bo, out);
}

// Round 3
// 259.902 us; speedup vs baseline: 1.3325x; 1.3325x over previous
//
#include <hip/hip_runtime.h>

typedef __bf16 bf16x8 __attribute__((ext_vector_type(8)));
typedef __bf16 bf16x4v __attribute__((ext_vector_type(4)));
typedef float floatx4 __attribute__((ext_vector_type(4)));

#define B_ 4
#define S_ 1024
#define E_ 768
#define H_ 12
#define HD_ 64

__device__ __forceinline__ void async16(const void* g, void* l) {
  __builtin_amdgcn_global_load_lds((const __attribute__((address_space(1))) void*)g,
                                   (__attribute__((address_space(3))) void*)l, 16, 0, 0);
}

__device__ __forceinline__ floatx4 mfma16(bf16x8 a, bf16x8 b, floatx4 c) {
  return __builtin_amdgcn_mfma_f32_16x16x32_bf16(a, b, c, 0, 0, 0);
}

// ---------------- fp32 -> bf16 conversion ----------------
__global__ __launch_bounds__(256) void cvt_in_kernel(
    const float* __restrict__ q, const float* __restrict__ k,
    const float* __restrict__ v, __bf16* __restrict__ dst) {
  const int z = blockIdx.z;
  const float* s = (z == 0) ? q : (z == 1) ? k : v;
  __bf16* d = dst + (size_t)z * (size_t)(B_ * S_ * E_);
  const size_t i8 = (size_t)blockIdx.x * 256 + threadIdx.x;
  const float4* sp = (const float4*)s + i8 * 2;
  float4 a = sp[0], b = sp[1];
  bf16x8 o;
  o[0] = (__bf16)a.x; o[1] = (__bf16)a.y; o[2] = (__bf16)a.z; o[3] = (__bf16)a.w;
  o[4] = (__bf16)b.x; o[5] = (__bf16)b.y; o[6] = (__bf16)b.z; o[7] = (__bf16)b.w;
  *(bf16x8*)(d + i8 * 8) = o;
}

__global__ __launch_bounds__(256) void cvt_w_kernel(
    const float* __restrict__ w0, const float* __restrict__ w1,
    const float* __restrict__ w2, const float* __restrict__ w3,
    __bf16* __restrict__ dst) {
  const int z = blockIdx.z;
  const float* s = (z == 0) ? w0 : (z == 1) ? w1 : (z == 2) ? w2 : w3;
  __bf16* d = dst + (size_t)z * (size_t)(E_ * E_);
  const size_t i8 = (size_t)blockIdx.x * 256 + threadIdx.x;
  const float4* sp = (const float4*)s + i8 * 2;
  float4 a = sp[0], b = sp[1];
  bf16x8 o;
  o[0] = (__bf16)a.x; o[1] = (__bf16)a.y; o[2] = (__bf16)a.z; o[3] = (__bf16)a.w;
  o[4] = (__bf16)b.x; o[5] = (__bf16)b.y; o[6] = (__bf16)b.z; o[7] = (__bf16)b.w;
  *(bf16x8*)(d + i8 * 8) = o;
}

// ---------------- QKV projection GEMM ----------------
// y = X @ W^T + bias ; X [4096,768] bf16, W [768,768] bf16 (row n = output feat)
// z=0 -> Qh [B,H,S,HD] scaled by 0.125 ; z=1 -> Kh [B,H,S,HD] ; z=2 -> Vt [B,H,HD,S]
__global__ __launch_bounds__(256, 3) void proj_qkv_kernel(
    const __bf16* __restrict__ Xq, const __bf16* __restrict__ Xk, const __bf16* __restrict__ Xv,
    const __bf16* __restrict__ Wq, const __bf16* __restrict__ Wk, const __bf16* __restrict__ Wv,
    const float* __restrict__ bq, const float* __restrict__ bk, const float* __restrict__ bv,
    __bf16* __restrict__ Qh, __bf16* __restrict__ Kh, __bf16* __restrict__ Vt) {
  const int z = blockIdx.z;
  const __bf16* X = (z == 0) ? Xq : (z == 1) ? Xk : Xv;
  const __bf16* W = (z == 0) ? Wq : (z == 1) ? Wk : Wv;
  const float* bias = (z == 0) ? bq : (z == 1) ? bk : bv;

  const int tid = threadIdx.x;
  const int wave = tid >> 6, lane = tid & 63;
  const int l15 = lane & 15, quad = lane >> 4;
  const int wr = wave >> 1, wc = wave & 1;
  const int bm = blockIdx.y * 128, bn = blockIdx.x * 128;

  __shared__ alignas(16) __bf16 As[128 * 32];
  __shared__ alignas(16) __bf16 Bs[128 * 32];

  floatx4 zf = {0.0f, 0.0f, 0.0f, 0.0f};
  floatx4 acc[4][4];
#pragma unroll
  for (int i = 0; i < 4; ++i)
#pragma unroll
    for (int j = 0; j < 4; ++j) acc[i][j] = zf;

  for (int kk = 0; kk < E_; kk += 32) {
#pragma unroll
    for (int c = 0; c < 2; ++c) {
      const int f = c * 256 + tid;
      const int r = f >> 2, kq = f & 3;
      async16(X + (size_t)(bm + r) * E_ + kk + kq * 8, &As[(c * 4 + wave) * 512]);
      async16(W + (size_t)(bn + r) * E_ + kk + kq * 8, &Bs[(c * 4 + wave) * 512]);
    }
    __syncthreads();
    bf16x8 af[4], bfr[4];
#pragma unroll
    for (int i = 0; i < 4; ++i)
      af[i] = *(const bf16x8*)&As[(wr * 64 + i * 16 + l15) * 32 + quad * 8];
#pragma unroll
    for (int j = 0; j < 4; ++j)
      bfr[j] = *(const bf16x8*)&Bs[(wc * 64 + j * 16 + l15) * 32 + quad * 8];
#pragma unroll
    for (int i = 0; i < 4; ++i)
#pragma unroll
      for (int j = 0; j < 4; ++j)
        acc[i][j] = mfma16(af[i], bfr[j], acc[i][j]);
    __syncthreads();
  }

#pragma unroll
  for (int j = 0; j < 4; ++j) {
    const int n = bn + wc * 64 + j * 16 + l15;
    const float bval = bias[n];
    const int hh = n >> 6, dd = n & 63;
    if (z < 2) {
      __bf16* dst = (z == 0) ? Qh : Kh;
      const float sc = (z == 0) ? 0.125f : 1.0f;
#pragma unroll
      for (int i = 0; i < 4; ++i) {
#pragma unroll
        for (int r = 0; r < 4; ++r) {
          const int m = bm + wr * 64 + i * 16 + quad * 4 + r;
          const int bb = m >> 10, ss = m & 1023;
          const float val = (acc[i][j][r] + bval) * sc;
          dst[(((size_t)bb * H_ + hh) * S_ + ss) * HD_ + dd] = (__bf16)val;
        }
      }
    } else {
#pragma unroll
      for (int i = 0; i < 4; ++i) {
        const int m0 = bm + wr * 64 + i * 16 + quad * 4;
        const int bb = m0 >> 10, ss0 = m0 & 1023;
        bf16x4v pk;
#pragma unroll
        for (int r = 0; r < 4; ++r) pk[r] = (__bf16)(acc[i][j][r] + bval);
        *(bf16x4v*)&Vt[(((size_t)bb * H_ + hh) * HD_ + dd) * S_ + ss0] = pk;
      }
    }
  }
}

// ---------------- output projection GEMM ----------------
__global__ __launch_bounds__(256, 3) void proj_out_kernel(
    const __bf16* __restrict__ X, const __bf16* __restrict__ W,
    const float* __restrict__ bias, float* __restrict__ out) {
  const int tid = threadIdx.x;
  const int wave = tid >> 6, lane = tid & 63;
  const int l15 = lane & 15, quad = lane >> 4;
  const int wr = wave >> 1, wc = wave & 1;
  const int bm = blockIdx.y * 128, bn = blockIdx.x * 128;

  __shared__ alignas(16) __bf16 As[128 * 32];
  __shared__ alignas(16) __bf16 Bs[128 * 32];

  floatx4 zf = {0.0f, 0.0f, 0.0f, 0.0f};
  floatx4 acc[4][4];
#pragma unroll
  for (int i = 0; i < 4; ++i)
#pragma unroll
    for (int j = 0; j < 4; ++j) acc[i][j] = zf;

  for (int kk = 0; kk < E_; kk += 32) {
#pragma unroll
    for (int c = 0; c < 2; ++c) {
      const int f = c * 256 + tid;
      const int r = f >> 2, kq = f & 3;
      async16(X + (size_t)(bm + r) * E_ + kk + kq * 8, &As[(c * 4 + wave) * 512]);
      async16(W + (size_t)(bn + r) * E_ + kk + kq * 8, &Bs[(c * 4 + wave) * 512]);
    }
    __syncthreads();
    bf16x8 af[4], bfr[4];
#pragma unroll
    for (int i = 0; i < 4; ++i)
      af[i] = *(const bf16x8*)&As[(wr * 64 + i * 16 + l15) * 32 + quad * 8];
#pragma unroll
    for (int j = 0; j < 4; ++j)
      bfr[j] = *(const bf16x8*)&Bs[(wc * 64 + j * 16 + l15) * 32 + quad * 8];
#pragma unroll
    for (int i = 0; i < 4; ++i)
#pragma unroll
      for (int j = 0; j < 4; ++j)
        acc[i][j] = mfma16(af[i], bfr[j], acc[i][j]);
    __syncthreads();
  }

#pragma unroll
  for (int j = 0; j < 4; ++j) {
    const int n = bn + wc * 64 + j * 16 + l15;
    const float bval = bias[n];
#pragma unroll
    for (int i = 0; i < 4; ++i) {
#pragma unroll
      for (int r = 0; r < 4; ++r) {
        const int m = bm + wr * 64 + i * 16 + quad * 4 + r;
        out[(size_t)m * E_ + n] = acc[i][j][r] + bval;
      }
    }
  }
}

// ---------------- fused flash attention (wave-independent) ----------------
// grid (16, 48): x = 64 q-rows (4 waves x 16), y = b*12+h. NO __syncthreads.
// Q/K/V fragments loaded global->VGPR in exact MFMA layout (no LDS staging).
// P (16x64) round-trips through wave-private LDS, row stride 72 (bank-safe).
// Mask applied after exp (softmax shift-invariance: running max over
// UNMASKED scores is exact); fully-masked rows -> l=0 -> output 0.
#define NEG_BIG (-1e30f)
#define PSTR 72
__global__ __launch_bounds__(256, 3) void attn_kernel(
    const __bf16* __restrict__ Qh, const __bf16* __restrict__ Kh,
    const __bf16* __restrict__ Vt, const int* __restrict__ mask,
    __bf16* __restrict__ XV) {
  const int tid = threadIdx.x;
  const int wave = tid >> 6, lane = tid & 63;
  const int l15 = lane & 15, quad = lane >> 4;
  const int bh = blockIdx.y;
  const int b = bh / H_, h = bh % H_;
  const int q0 = blockIdx.x * 64 + wave * 16;  // this wave's 16 q-rows

  __shared__ alignas(16) __bf16 Ps[4 * 16 * PSTR];  // 9 KB, wave-private slices
  __bf16* Pw = &Ps[wave * 16 * PSTR];

  // Q fragments straight from global: A[m=l15][k=ks*32+quad*8+j]
  const __bf16* qb = Qh + ((size_t)bh * S_ + q0) * HD_;
  bf16x8 af[2];
  af[0] = *(const bf16x8*)(qb + (size_t)l15 * HD_ + quad * 8);
  af[1] = *(const bf16x8*)(qb + (size_t)l15 * HD_ + 32 + quad * 8);

  floatx4 zf = {0.0f, 0.0f, 0.0f, 0.0f};
  floatx4 o[4];
  float mrow[4], lrow[4];
#pragma unroll
  for (int jd = 0; jd < 4; ++jd) o[jd] = zf;
#pragma unroll
  for (int r = 0; r < 4; ++r) { mrow[r] = NEG_BIG; lrow[r] = 0.0f; }

  const int* mbase = mask + ((size_t)b * S_ + q0) * S_;
  const __bf16* kb = Kh + (size_t)bh * S_ * HD_;
  const __bf16* vb = Vt + (size_t)bh * HD_ * S_;

  for (int kt = 0; kt < 16; ++kt) {
    const int k0 = kt * 64;

    // K fragments: B[n=key=j*16+l15][k=ks*32+quad*8+..]
    bf16x8 bk[4][2];
#pragma unroll
    for (int j = 0; j < 4; ++j)
#pragma unroll
      for (int ks = 0; ks < 2; ++ks)
        bk[j][ks] = *(const bf16x8*)(kb + (size_t)(k0 + j * 16 + l15) * HD_ + ks * 32 + quad * 8);

    // V fragments: B[n=d=jd*16+l15][k=key=ks2*32+quad*8+..]
    bf16x8 bvf[4][2];
#pragma unroll
    for (int jd = 0; jd < 4; ++jd)
#pragma unroll
      for (int ks2 = 0; ks2 < 2; ++ks2)
        bvf[jd][ks2] = *(const bf16x8*)(vb + (size_t)(jd * 16 + l15) * S_ + k0 + ks2 * 32 + quad * 8);

    // mask values for this tile (needed only after exp)
    int mv[4][4];
#pragma unroll
    for (int j = 0; j < 4; ++j)
#pragma unroll
      for (int r = 0; r < 4; ++r)
        mv[j][r] = mbase[(size_t)(quad * 4 + r) * S_ + k0 + j * 16 + l15];

    // scores: S = Q K^T (Q pre-scaled by 1/8). C-layout: col=l15(key), row=quad*4+r(q)
    floatx4 sc[4];
#pragma unroll
    for (int j = 0; j < 4; ++j) sc[j] = zf;
#pragma unroll
    for (int j = 0; j < 4; ++j) {
      sc[j] = mfma16(af[0], bk[j][0], sc[j]);
      sc[j] = mfma16(af[1], bk[j][1], sc[j]);
    }

    // online softmax over UNMASKED scores (shift-invariant; mask applied to p)
    float tmax[4];
#pragma unroll
    for (int r = 0; r < 4; ++r) {
      float mx = sc[0][r];
#pragma unroll
      for (int j = 1; j < 4; ++j) mx = fmaxf(mx, sc[j][r]);
      tmax[r] = mx;
    }
#pragma unroll
    for (int sh = 1; sh < 16; sh <<= 1)
#pragma unroll
      for (int r = 0; r < 4; ++r) tmax[r] = fmaxf(tmax[r], __shfl_xor(tmax[r], sh, 64));
    float mnew[4], alpha[4], tsum[4];
#pragma unroll
    for (int r = 0; r < 4; ++r) {
      mnew[r] = fmaxf(mrow[r], tmax[r]);
      alpha[r] = __expf(mrow[r] - mnew[r]);
      mrow[r] = mnew[r];
      tsum[r] = 0.0f;
    }
#pragma unroll
    for (int j = 0; j < 4; ++j)
#pragma unroll
      for (int r = 0; r < 4; ++r) {
        float p = __expf(sc[j][r] - mnew[r]);
        p = mv[j][r] ? p : 0.0f;
        tsum[r] += p;
        Pw[(quad * 4 + r) * PSTR + j * 16 + l15] = (__bf16)p;
      }
#pragma unroll
    for (int sh = 1; sh < 16; sh <<= 1)
#pragma unroll
      for (int r = 0; r < 4; ++r) tsum[r] += __shfl_xor(tsum[r], sh, 64);
#pragma unroll
    for (int r = 0; r < 4; ++r) lrow[r] = lrow[r] * alpha[r] + tsum[r];
#pragma unroll
    for (int jd = 0; jd < 4; ++jd)
#pragma unroll
      for (int r = 0; r < 4; ++r) o[jd][r] *= alpha[r];

    // O += P V  (P wave-private LDS write->read, in order within wave)
#pragma unroll
    for (int ks2 = 0; ks2 < 2; ++ks2) {
      bf16x8 pa = *(const bf16x8*)&Pw[l15 * PSTR + ks2 * 32 + quad * 8];
#pragma unroll
      for (int jd = 0; jd < 4; ++jd) o[jd] = mfma16(pa, bvf[jd][ks2], o[jd]);
    }
  }

  // epilogue: normalize, store XV [B,S,E] bf16
  float linv[4];
#pragma unroll
  for (int r = 0; r < 4; ++r) linv[r] = (lrow[r] > 0.0f) ? (1.0f / lrow[r]) : 0.0f;
  __bf16* xbase = XV + ((size_t)b * S_ + q0) * E_ + h * HD_;
#pragma unroll
  for (int jd = 0; jd < 4; ++jd)
#pragma unroll
    for (int r = 0; r < 4; ++r)
      xbase[(size_t)(quad * 4 + r) * E_ + jd * 16 + l15] = (__bf16)(o[jd][r] * linv[r]);
}

extern "C" void kernel_launch(void* const* d_in, const int* in_sizes, int n_in,
                              void* d_out, int out_size, void* d_ws, size_t ws_size,
                              hipStream_t stream) {
  const float* query = (const float*)d_in[0];
  const float* key   = (const float*)d_in[1];
  const float* value = (const float*)d_in[2];
  const int*   mask  = (const int*)d_in[3];
  const float* Wq = (const float*)d_in[4];
  const float* bq = (const float*)d_in[5];
  const float* Wk = (const float*)d_in[6];
  const float* bk = (const float*)d_in[7];
  const float* Wv = (const float*)d_in[8];
  const float* bv = (const float*)d_in[9];
  const float* Wo = (const float*)d_in[10];
  const float* bo = (const float*)d_in[11];
  float* out = (float*)d_out;

  const size_t NX = (size_t)B_ * S_ * E_;  // 3145728
  const size_t NW = (size_t)E_ * E_;       // 589824
  __bf16* ws = (__bf16*)d_ws;
  __bf16* xq  = ws;
  __bf16* xk  = xq + NX;
  __bf16* xv  = xk + NX;
  __bf16* wqb = xv + NX;
  __bf16* wkb = wqb + NW;
  __bf16* wvb = wkb + NW;
  __bf16* wob = wvb + NW;
  __bf16* Qh  = wob + NW;
  __bf16* Kh  = Qh + NX;
  __bf16* Vt  = Kh + NX;
  __bf16* XVb = Vt + NX;

  cvt_in_kernel<<<dim3(1536, 1, 3), 256, 0, stream>>>(query, key, value, xq);
  cvt_w_kernel<<<dim3(288, 1, 4), 256, 0, stream>>>(Wq, Wk, Wv, Wo, wqb);
  proj_qkv_kernel<<<dim3(6, 32, 3), 256, 0, stream>>>(xq, xk, xv, wqb, wkb, wvb,
                                                      bq, bk, bv, Qh, Kh, Vt);
  attn_kernel<<<dim3(16, 48), 256, 0, stream>>>(Qh, Kh, Vt, mask, XVb);
  proj_out_kernel<<<dim3(6, 32), 256, 0, stream>>>(XVb, wob, bo, out);
}